// Round 5
// baseline (265.624 us; speedup 1.0000x reference)
//
#include <hip/hip_runtime.h>
#include <hip/hip_bf16.h>
#include <type_traits>

typedef __hip_bfloat16 bf16;
typedef __attribute__((ext_vector_type(4))) float f32x4;
typedef __attribute__((ext_vector_type(8))) short s16x8;

#define DEVINL __device__ __forceinline__

DEVINL s16x8 load16B(const void* p) {
  s16x8 v;
  __builtin_memcpy(&v, __builtin_assume_aligned(p, 16), 16);
  return v;
}
DEVINL void store16B(void* p, s16x8 v) {
  __builtin_memcpy(__builtin_assume_aligned(p, 16), &v, 16);
}
// load 8 consecutive f32, downcast to 8 bf16 packed in s16x8
DEVINL s16x8 cvt8(const float* p) {
  f32x4 a, b;
  __builtin_memcpy(&a, __builtin_assume_aligned(p, 16), 16);
  __builtin_memcpy(&b, __builtin_assume_aligned(p + 4, 16), 16);
  union { s16x8 v; bf16 h[8]; } u;
#pragma unroll
  for (int i = 0; i < 4; i++) {
    u.h[i] = __float2bfloat16(a[i]);
    u.h[4 + i] = __float2bfloat16(b[i]);
  }
  return u.v;
}

static constexpr int SEQ = 2048;   // L
// DX = 1024, H = 16, Dh = 64, B = 2 hard-coded below.

// ------ weight transpose + downcast: dst[n*1024+k] = bf16(src[k*1024+n]) ---
__global__ __launch_bounds__(256) void k_transpose(
    const float* __restrict__ Wq, const float* __restrict__ Wk,
    const float* __restrict__ Wv, const float* __restrict__ Wo,
    bf16* __restrict__ dst) {
  __shared__ float t[64][65];
  const float* src = blockIdx.z == 0 ? Wq : blockIdx.z == 1 ? Wk
                   : blockIdx.z == 2 ? Wv : Wo;
  bf16* out = dst + (size_t)blockIdx.z * 1024 * 1024;
  const int r0 = blockIdx.y * 64, c0 = blockIdx.x * 64;
#pragma unroll
  for (int i = 0; i < 16; i++) {
    int e = i * 256 + threadIdx.x;
    int r = e >> 6, c = e & 63;
    t[r][c] = src[(size_t)(r0 + r) * 1024 + c0 + c];
  }
  __syncthreads();
#pragma unroll
  for (int i = 0; i < 16; i++) {
    int e = i * 256 + threadIdx.x;
    int r = e >> 6, c = e & 63;
    out[(size_t)(c0 + r) * 1024 + r0 + c] = __float2bfloat16(t[c][r]);
  }
}

// ------------- C = X[4096,1024] @ W + bias, W given pre-transposed ---------
// WT is [n][k] bf16 row-major; X is f32 (converted during staging) or bf16.
// MODE 0: dst per-head token-major [bh][l][64]   (Q, K)       -> bf16
// MODE 1: dst per-head d-major     [bh][64][l]   (V^T)        -> bf16
// MODE 2: dst natural              [m][1024]     (final out)  -> f32
template <int MODE, typename XT>
__global__ __launch_bounds__(256) void k_gemm_bt(
    const XT* __restrict__ X, const bf16* __restrict__ WT,
    const float* __restrict__ bias, void* __restrict__ dstv) {
  __shared__ alignas(16) bf16 As[128 * 32];
  __shared__ alignas(16) bf16 Bs[128 * 32];
  const int tid = threadIdx.x;
  const int w = tid >> 6, lane = tid & 63, lg = lane >> 4, li = lane & 15;
  const int wm = w >> 1, wn = w & 1;
  const int m0 = blockIdx.y * 128, n0 = blockIdx.x * 128;

  f32x4 acc[4][4] = {};

  for (int kt = 0; kt < 32; ++kt) {
    const int k0 = kt * 32;
    s16x8 ra[2], rb[2];
#pragma unroll
    for (int i = 0; i < 2; i++) {
      int c = i * 256 + tid;              // 512 chunks of 8 elems = [128][32]
      int r = c >> 2, kk = (c & 3) * 8;
      if constexpr (std::is_same_v<XT, float>)
        ra[i] = cvt8(X + (size_t)(m0 + r) * 1024 + k0 + kk);
      else
        ra[i] = load16B(X + (size_t)(m0 + r) * 1024 + k0 + kk);
      rb[i] = load16B(WT + (size_t)(n0 + r) * 1024 + k0 + kk);
    }
    __syncthreads();                      // prev iter's LDS reads done
#pragma unroll
    for (int i = 0; i < 2; i++) {
      int c = i * 256 + tid;
      int byt = (c * 16) ^ (((c >> 2) & 7) << 4);   // row = c>>2, XOR-swizzle
      store16B((char*)As + byt, ra[i]);
      store16B((char*)Bs + byt, rb[i]);
    }
    __syncthreads();
    s16x8 af[4], bfv[4];
#pragma unroll
    for (int i = 0; i < 4; i++) {
      int row = wm * 64 + i * 16 + li;
      af[i] = load16B((char*)As + ((row * 64 + lg * 16) ^ ((row & 7) << 4)));
    }
#pragma unroll
    for (int j = 0; j < 4; j++) {
      int row = wn * 64 + j * 16 + li;
      bfv[j] = load16B((char*)Bs + ((row * 64 + lg * 16) ^ ((row & 7) << 4)));
    }
#pragma unroll
    for (int i = 0; i < 4; i++)
#pragma unroll
      for (int j = 0; j < 4; j++)
        acc[i][j] = __builtin_amdgcn_mfma_f32_16x16x32_bf16(af[i], bfv[j],
                                                            acc[i][j], 0, 0, 0);
  }

  // C/D layout: lane reg r -> row (lane>>4)*4+r, col lane&15 (m89/m91)
#pragma unroll
  for (int j = 0; j < 4; j++) {
    const int n = n0 + wn * 64 + j * 16 + li;
    const float bv = bias[n];
#pragma unroll
    for (int i = 0; i < 4; i++) {
      const int mrow = m0 + wm * 64 + i * 16 + lg * 4;
      f32x4 a = acc[i][j];
      if constexpr (MODE == 2) {
        float* dst = (float*)dstv;
#pragma unroll
        for (int r = 0; r < 4; r++)
          dst[(size_t)(mrow + r) * 1024 + n] = a[r] + bv;
      } else if constexpr (MODE == 0) {
        bf16* dst = (bf16*)dstv;
#pragma unroll
        for (int r = 0; r < 4; r++) {
          int m = mrow + r;   // b = m>>11, l = m&2047, h = n>>6, d = n&63
          size_t idx =
              ((size_t)((m >> 11) * 16 + (n >> 6)) * SEQ + (m & 2047)) * 64 +
              (n & 63);
          dst[idx] = __float2bfloat16(a[r] + bv);
        }
      } else {  // MODE 1: V^T, 4 consecutive tokens same d -> one 8B store
        bf16* dst = (bf16*)dstv;
        size_t base =
            ((size_t)((mrow >> 11) * 16 + (n >> 6)) * 64 + (n & 63)) * SEQ +
            (mrow & 2047);
        bf16 tmp[4];
#pragma unroll
        for (int r = 0; r < 4; r++) tmp[r] = __float2bfloat16(a[r] + bv);
        __builtin_memcpy(__builtin_assume_aligned(dst + base, 8), tmp, 8);
      }
    }
  }
}

// ------------------------- causal flash attention --------------------------
// grid (qblk=32, bh=32), 256 thr = 4 waves x 16 q-rows. KBLK = 64.
__global__ __launch_bounds__(256) void k_attn(
    const bf16* __restrict__ qb, const bf16* __restrict__ kb,
    const bf16* __restrict__ vtb, bf16* __restrict__ attn) {
  __shared__ alignas(16) bf16 Ks[64 * 64];    // [k][d], XOR-swizzled
  __shared__ alignas(16) bf16 Vts[64 * 64];   // [d][k], XOR-swizzled
  __shared__ alignas(16) bf16 Ps[4][16 * 72]; // per-wave P, +8 pad
  const int tid = threadIdx.x;
  const int w = tid >> 6, lane = tid & 63, lg = lane >> 4, li = lane & 15;
  const int bh = blockIdx.y, qblk = blockIdx.x;
  const int q0 = qblk * 64;
  const int qrow = q0 + w * 16;
  const bf16* qh = qb + (size_t)bh * SEQ * 64;
  const bf16* kh = kb + (size_t)bh * SEQ * 64;
  const bf16* vth = vtb + (size_t)bh * 64 * SEQ;

  s16x8 aq[2];  // Q fragments held in registers all kernel
#pragma unroll
  for (int c = 0; c < 2; c++)
    aq[c] = load16B(qh + (size_t)(qrow + li) * 64 + c * 32 + lg * 8);

  f32x4 o[4] = {};
  float m_run[4] = {-1e38f, -1e38f, -1e38f, -1e38f};
  float l_run[4] = {0.f, 0.f, 0.f, 0.f};
  const float scale = 0.03125f;  // 1/sqrt(DX=1024) per reference

  for (int kbk = 0; kbk <= qblk; ++kbk) {
    const int k0 = kbk * 64;
    s16x8 rk[2], rv[2];
#pragma unroll
    for (int i = 0; i < 2; i++) {
      int c = i * 256 + tid;
      rk[i] = load16B(kh + (size_t)k0 * 64 + c * 8);         // contiguous 8KB
      int d = c >> 3, kk = (c & 7) * 8;
      rv[i] = load16B(vth + (size_t)d * SEQ + k0 + kk);
    }
    __syncthreads();
#pragma unroll
    for (int i = 0; i < 2; i++) {
      int c = i * 256 + tid;
      int byt = (c * 16) ^ (((c >> 3) & 7) << 4);  // row = c>>3 (128B rows)
      store16B((char*)Ks + byt, rk[i]);
      store16B((char*)Vts + byt, rv[i]);
    }
    __syncthreads();

    // S = Q K^T : A-frag = Q rows (li), B-frag = K rows (li) -> X*Y^T
    f32x4 s[4];
#pragma unroll
    for (int t = 0; t < 4; t++) {
      f32x4 z = {};
#pragma unroll
      for (int c = 0; c < 2; c++) {
        int row = t * 16 + li;
        s16x8 bk = load16B((char*)Ks +
                           ((row * 128 + c * 64 + lg * 16) ^ ((row & 7) << 4)));
        z = __builtin_amdgcn_mfma_f32_16x16x32_bf16(aq[c], bk, z, 0, 0, 0);
      }
      s[t] = z;
    }

    if (kbk == qblk) {  // diagonal block: per-element causal mask
#pragma unroll
      for (int t = 0; t < 4; t++)
#pragma unroll
        for (int r = 0; r < 4; r++) {
          int kg = k0 + t * 16 + li;
          int qg = qrow + lg * 4 + r;
          if (kg > qg) s[t][r] = -1e30f;
        }
    }

    // online softmax: rows live on 16-lane groups (same lg), cols = li + 16t
    float p[4][4];
    float corr[4];
#pragma unroll
    for (int r = 0; r < 4; r++) {
      float mr =
          fmaxf(fmaxf(s[0][r], s[1][r]), fmaxf(s[2][r], s[3][r])) * scale;
#pragma unroll
      for (int msk = 1; msk < 16; msk <<= 1) mr = fmaxf(mr, __shfl_xor(mr, msk));
      float mn = fmaxf(m_run[r], mr);
      float sum = 0.f;
#pragma unroll
      for (int t = 0; t < 4; t++) {
        float pv = __expf(s[t][r] * scale - mn);
        p[t][r] = pv;
        sum += pv;
      }
#pragma unroll
      for (int msk = 1; msk < 16; msk <<= 1) sum += __shfl_xor(sum, msk);
      float cr = __expf(m_run[r] - mn);
      l_run[r] = l_run[r] * cr + sum;
      m_run[r] = mn;
      corr[r] = cr;
    }
#pragma unroll
    for (int t = 0; t < 4; t++)
#pragma unroll
      for (int r = 0; r < 4; r++) o[t][r] *= corr[r];

    // P -> per-wave LDS (acc layout) -> re-read as A-fragments
#pragma unroll
    for (int t = 0; t < 4; t++)
#pragma unroll
      for (int r = 0; r < 4; r++)
        Ps[w][(lg * 4 + r) * 72 + t * 16 + li] = __float2bfloat16(p[t][r]);

    s16x8 ap[2];
#pragma unroll
    for (int c = 0; c < 2; c++)
      ap[c] = load16B(&Ps[w][li * 72 + c * 32 + lg * 8]);

    // O += P @ V : B-frag from V^T rows (d = li+16t), elems = k
#pragma unroll
    for (int t = 0; t < 4; t++) {
#pragma unroll
      for (int c = 0; c < 2; c++) {
        int row = t * 16 + li;
        s16x8 bv = load16B((char*)Vts +
                           ((row * 128 + c * 64 + lg * 16) ^ ((row & 7) << 4)));
        o[t] = __builtin_amdgcn_mfma_f32_16x16x32_bf16(ap[c], bv, o[t], 0, 0, 0);
      }
    }
  }

  const int b = bh >> 4, h = bh & 15;
#pragma unroll
  for (int t = 0; t < 4; t++)
#pragma unroll
    for (int r = 0; r < 4; r++) {
      float val = o[t][r] / l_run[r];
      size_t idx = (size_t)(b * SEQ + qrow + lg * 4 + r) * 1024 + h * 64 +
                   t * 16 + li;
      attn[idx] = __float2bfloat16(val);
    }
}

extern "C" void kernel_launch(void* const* d_in, const int* in_sizes, int n_in,
                              void* d_out, int out_size, void* d_ws,
                              size_t ws_size, hipStream_t stream) {
  (void)in_sizes; (void)n_in; (void)out_size; (void)ws_size;
  const float* value = (const float*)d_in[0];
  const float* key   = (const float*)d_in[1];
  const float* query = (const float*)d_in[2];
  // d_in[3] = mask (int32 causal tril) — causality applied analytically
  const float* Wq_w = (const float*)d_in[4];
  const float* Wq_b = (const float*)d_in[5];
  const float* Wk_w = (const float*)d_in[6];
  const float* Wk_b = (const float*)d_in[7];
  const float* Wv_w = (const float*)d_in[8];
  const float* Wv_b = (const float*)d_in[9];
  // d_in[10..11] = Wr (computed-then-deleted in reference) — skipped
  const float* wo_w = (const float*)d_in[12];
  const float* wo_b = (const float*)d_in[13];

  bf16* ws = (bf16*)d_ws;
  const size_t MM = 1024 * 1024;
  bf16* WqT  = ws;             // [n][k] transposed bf16 weights
  bf16* WkT  = ws + 1 * MM;
  bf16* WvT  = ws + 2 * MM;
  bf16* WoT  = ws + 3 * MM;
  bf16* qbuf = ws + 4 * MM;    // [bh][l][64]
  bf16* kbuf = ws + 8 * MM;    // [bh][l][64]
  bf16* vtbf = ws + 12 * MM;   // [bh][64][l]
  bf16* abuf = ws + 16 * MM;   // [m][1024]  (total 40 MB)

  k_transpose<<<dim3(16, 16, 4), 256, 0, stream>>>(Wq_w, Wk_w, Wv_w, wo_w, ws);
  k_gemm_bt<0, float><<<dim3(8, 32), 256, 0, stream>>>(query, WqT, Wq_b, qbuf);
  k_gemm_bt<0, float><<<dim3(8, 32), 256, 0, stream>>>(key,   WkT, Wk_b, kbuf);
  k_gemm_bt<1, float><<<dim3(8, 32), 256, 0, stream>>>(value, WvT, Wv_b, vtbf);
  k_attn<<<dim3(32, 32), 256, 0, stream>>>(qbuf, kbuf, vtbf, abuf);
  k_gemm_bt<2, bf16><<<dim3(8, 32), 256, 0, stream>>>(abuf, WoT, wo_b, d_out);
}

// Round 6
// 194.797 us; speedup vs baseline: 1.3636x; 1.3636x over previous
//
#include <hip/hip_runtime.h>
#include <hip/hip_bf16.h>

typedef __hip_bfloat16 bf16;
typedef __attribute__((ext_vector_type(4))) float f32x4;
typedef __attribute__((ext_vector_type(8))) short s16x8;

#define DEVINL __device__ __forceinline__

DEVINL s16x8 load16B(const void* p) {
  s16x8 v;
  __builtin_memcpy(&v, __builtin_assume_aligned(p, 16), 16);
  return v;
}
DEVINL void store16B(void* p, s16x8 v) {
  __builtin_memcpy(__builtin_assume_aligned(p, 16), &v, 16);
}
// load 8 consecutive f32, downcast to 8 bf16 packed in s16x8
DEVINL s16x8 cvt8(const float* p) {
  f32x4 a, b;
  __builtin_memcpy(&a, __builtin_assume_aligned(p, 16), 16);
  __builtin_memcpy(&b, __builtin_assume_aligned(p + 4, 16), 16);
  union { s16x8 v; bf16 h[8]; } u;
#pragma unroll
  for (int i = 0; i < 4; i++) {
    u.h[i] = __float2bfloat16(a[i]);
    u.h[4 + i] = __float2bfloat16(b[i]);
  }
  return u.v;
}
// async global->LDS 16B (m97 pattern): LDS dest = wave-uniform base + lane*16
DEVINL void gload_lds16(const bf16* g, bf16* l) {
  __builtin_amdgcn_global_load_lds(
      (__attribute__((address_space(1))) void*)(void*)const_cast<bf16*>(g),
      (__attribute__((address_space(3))) void*)l, 16, 0, 0);
}

static constexpr int SEQ = 2048;   // L
// DX = 1024, H = 16, Dh = 64, B = 2 hard-coded below.

// ------ weight transpose + downcast: dst[n*1024+k] = bf16(src[k*1024+n]) ---
__global__ __launch_bounds__(256) void k_transpose(
    const float* __restrict__ Wq, const float* __restrict__ Wk,
    const float* __restrict__ Wv, const float* __restrict__ Wo,
    bf16* __restrict__ dst) {
  __shared__ float t[64][65];
  const float* src = blockIdx.z == 0 ? Wq : blockIdx.z == 1 ? Wk
                   : blockIdx.z == 2 ? Wv : Wo;
  bf16* out = dst + (size_t)blockIdx.z * 1024 * 1024;
  const int r0 = blockIdx.y * 64, c0 = blockIdx.x * 64;
#pragma unroll
  for (int i = 0; i < 16; i++) {
    int e = i * 256 + threadIdx.x;
    int r = e >> 6, c = e & 63;
    t[r][c] = src[(size_t)(r0 + r) * 1024 + c0 + c];
  }
  __syncthreads();
#pragma unroll
  for (int i = 0; i < 16; i++) {
    int e = i * 256 + threadIdx.x;
    int r = e >> 6, c = e & 63;
    out[(size_t)(c0 + r) * 1024 + r0 + c] = __float2bfloat16(t[c][r]);
  }
}

// ------------------- f32 -> bf16 elementwise (4.19M elems) -----------------
__global__ __launch_bounds__(256) void k_cvt(const float* __restrict__ src,
                                             bf16* __restrict__ dst) {
  size_t i = ((size_t)blockIdx.x * 256 + threadIdx.x) * 8;
  store16B(dst + i, cvt8(src + i));
}

// -------- shared GEMM core: C = X[4096,1024] @ WT^T + bias ----------------
// X, WT bf16 row-major [*,1024]; staging via global_load_lds dwordx4 (m97).
// mode 0: dst bf16 per-head token-major [bh][l][64], value scaled (Q/K)
// mode 1: dst bf16 per-head d-major     [bh][64][l]  (V^T)
// mode 2: dst f32 natural               [m][1024]    (final out)
DEVINL void gemm_core(const bf16* __restrict__ X, const bf16* __restrict__ WT,
                      const float* __restrict__ bias, void* __restrict__ dstv,
                      const int mode, const float scale, const int m0,
                      const int n0) {
  __shared__ alignas(16) bf16 As[128 * 32];
  __shared__ alignas(16) bf16 Bs[128 * 32];
  const int tid = threadIdx.x;
  const int w = tid >> 6, lane = tid & 63, lg = lane >> 4, li = lane & 15;
  const int wm = w >> 1, wn = w & 1;

  f32x4 acc[4][4] = {};

  for (int kt = 0; kt < 32; ++kt) {
    const int k0 = kt * 32;
#pragma unroll
    for (int j = 0; j < 2; j++) {
      const int cb = (j * 4 + w) * 64;       // wave-uniform chunk base
      const int c = cb + lane;               // 16B chunk: row=c>>2, k=(c&3)*8
      const int r = c >> 2, kk = (c & 3) * 8;
      gload_lds16(X + (size_t)(m0 + r) * 1024 + k0 + kk, As + cb * 8);
      gload_lds16(WT + (size_t)(n0 + r) * 1024 + k0 + kk, Bs + cb * 8);
    }
    __syncthreads();   // compiler drains vmcnt before s_barrier (m97)
    s16x8 af[4], bfv[4];
#pragma unroll
    for (int i = 0; i < 4; i++)
      af[i] = load16B((char*)As + (wm * 64 + i * 16 + li) * 64 + lg * 16);
#pragma unroll
    for (int j = 0; j < 4; j++)
      bfv[j] = load16B((char*)Bs + (wn * 64 + j * 16 + li) * 64 + lg * 16);
#pragma unroll
    for (int i = 0; i < 4; i++)
#pragma unroll
      for (int j = 0; j < 4; j++)
        acc[i][j] = __builtin_amdgcn_mfma_f32_16x16x32_bf16(af[i], bfv[j],
                                                            acc[i][j], 0, 0, 0);
    __syncthreads();   // all waves done reading before next overwrite
  }

  // C/D layout: lane reg r -> row (lane>>4)*4+r, col lane&15 (m89/m91)
#pragma unroll
  for (int j = 0; j < 4; j++) {
    const int n = n0 + wn * 64 + j * 16 + li;
    const float bv = bias[n];
#pragma unroll
    for (int i = 0; i < 4; i++) {
      const int mrow = m0 + wm * 64 + i * 16 + lg * 4;
      f32x4 a = acc[i][j];
      if (mode == 2) {
        float* dst = (float*)dstv;
#pragma unroll
        for (int r = 0; r < 4; r++)
          dst[(size_t)(mrow + r) * 1024 + n] = a[r] + bv;
      } else if (mode == 0) {
        bf16* dst = (bf16*)dstv;
#pragma unroll
        for (int r = 0; r < 4; r++) {
          int m = mrow + r;   // b=m>>11, l=m&2047, h=n>>6, d=n&63
          size_t idx =
              ((size_t)((m >> 11) * 16 + (n >> 6)) * SEQ + (m & 2047)) * 64 +
              (n & 63);
          dst[idx] = __float2bfloat16((a[r] + bv) * scale);
        }
      } else {  // mode 1: V^T, 4 consecutive tokens same d -> one 8B store
        bf16* dst = (bf16*)dstv;
        size_t base =
            ((size_t)((mrow >> 11) * 16 + (n >> 6)) * 64 + (n & 63)) * SEQ +
            (mrow & 2047);
        bf16 tmp[4];
#pragma unroll
        for (int r = 0; r < 4; r++) tmp[r] = __float2bfloat16(a[r] + bv);
        __builtin_memcpy(__builtin_assume_aligned(dst + base, 8), tmp, 8);
      }
    }
  }
}

// fused Q/K/V projections: z selects input/weight/bias/dst/mode/scale
__global__ __launch_bounds__(256) void k_gemm_qkv(
    const bf16* __restrict__ qx, const bf16* __restrict__ kx,
    const bf16* __restrict__ vx, const bf16* __restrict__ WTbase,
    const float* __restrict__ qb, const float* __restrict__ kb,
    const float* __restrict__ vb, bf16* __restrict__ qo,
    bf16* __restrict__ ko, bf16* __restrict__ vto, int zbase) {
  const int z = zbase + blockIdx.z;
  const bf16* X = z == 0 ? qx : z == 1 ? kx : vx;
  const bf16* WT = WTbase + (size_t)z * 1048576;
  const float* bias = z == 0 ? qb : z == 1 ? kb : vb;
  void* dst = z == 0 ? (void*)qo : z == 1 ? (void*)ko : (void*)vto;
  gemm_core(X, WT, bias, dst, z == 2 ? 1 : 0, z == 0 ? 0.03125f : 1.0f,
            blockIdx.y * 128, blockIdx.x * 128);
}

__global__ __launch_bounds__(256) void k_gemm_out(
    const bf16* __restrict__ X, const bf16* __restrict__ WT,
    const float* __restrict__ bias, float* __restrict__ out) {
  gemm_core(X, WT, bias, out, 2, 1.0f, blockIdx.y * 128, blockIdx.x * 128);
}

// ------------------------- causal flash attention --------------------------
// grid (32,32), 256 thr = 4 waves x 16 q-rows, KBLK=64.
// longest-first (qblk = 31-bx) + register prefetch of next K/V tile (T14).
// Q is pre-scaled by 1/32 in the projection epilogue.
__global__ __launch_bounds__(256) void k_attn(
    const bf16* __restrict__ qb, const bf16* __restrict__ kb,
    const bf16* __restrict__ vtb, bf16* __restrict__ attn) {
  __shared__ alignas(16) bf16 Ks[64 * 64];    // [k][d], XOR-swizzled
  __shared__ alignas(16) bf16 Vts[64 * 64];   // [d][k], XOR-swizzled
  __shared__ alignas(16) bf16 Ps[4][16 * 72]; // per-wave P, +8 pad
  const int tid = threadIdx.x;
  const int w = tid >> 6, lane = tid & 63, lg = lane >> 4, li = lane & 15;
  const int bh = blockIdx.y;
  const int qblk = 31 - blockIdx.x;           // longest blocks dispatch first
  const int qrow = qblk * 64 + w * 16;
  const bf16* qh = qb + (size_t)bh * SEQ * 64;
  const bf16* kh = kb + (size_t)bh * SEQ * 64;
  const bf16* vth = vtb + (size_t)bh * 64 * SEQ;

  s16x8 aq[2];  // Q fragments held in registers all kernel
#pragma unroll
  for (int c = 0; c < 2; c++)
    aq[c] = load16B(qh + (size_t)(qrow + li) * 64 + c * 32 + lg * 8);

  f32x4 o[4] = {};
  float m_run[4] = {-1e38f, -1e38f, -1e38f, -1e38f};
  float l_run[4] = {0.f, 0.f, 0.f, 0.f};

  s16x8 rk[2], rv[2];  // prefetch registers
#pragma unroll
  for (int i = 0; i < 2; i++) {      // prefetch tile 0
    int c = i * 256 + tid;
    rk[i] = load16B(kh + (size_t)c * 8);
    int d = c >> 3, kk = (c & 7) * 8;
    rv[i] = load16B(vth + (size_t)d * SEQ + kk);
  }

  for (int kbk = 0; kbk <= qblk; ++kbk) {
    __syncthreads();                 // prev iter's LDS reads done
#pragma unroll
    for (int i = 0; i < 2; i++) {
      int c = i * 256 + tid;
      int byt = (c * 16) ^ (((c >> 3) & 7) << 4);  // row = c>>3 (128B rows)
      store16B((char*)Ks + byt, rk[i]);
      store16B((char*)Vts + byt, rv[i]);
    }
    __syncthreads();
    if (kbk < qblk) {                // issue next tile's loads before compute
      const int kn = (kbk + 1) * 64;
#pragma unroll
      for (int i = 0; i < 2; i++) {
        int c = i * 256 + tid;
        rk[i] = load16B(kh + (size_t)kn * 64 + c * 8);
        int d = c >> 3, kk = (c & 7) * 8;
        rv[i] = load16B(vth + (size_t)d * SEQ + kn + kk);
      }
    }

    // S = Q K^T (Q pre-scaled): A-frag = Q rows, B-frag = K rows
    f32x4 s[4];
#pragma unroll
    for (int t = 0; t < 4; t++) {
      f32x4 z = {};
#pragma unroll
      for (int c = 0; c < 2; c++) {
        int row = t * 16 + li;
        s16x8 bk = load16B((char*)Ks +
                           ((row * 128 + c * 64 + lg * 16) ^ ((row & 7) << 4)));
        z = __builtin_amdgcn_mfma_f32_16x16x32_bf16(aq[c], bk, z, 0, 0, 0);
      }
      s[t] = z;
    }

    if (kbk == qblk) {  // diagonal block: per-element causal mask
      const int kb0 = kbk * 64;
#pragma unroll
      for (int t = 0; t < 4; t++)
#pragma unroll
        for (int r = 0; r < 4; r++) {
          int kg = kb0 + t * 16 + li;
          int qg = qrow + lg * 4 + r;
          if (kg > qg) s[t][r] = -1e30f;
        }
    }

    // online softmax: row q = lg*4+r lives on the 16 lanes sharing lg
    float p[4][4];
    float corr[4];
#pragma unroll
    for (int r = 0; r < 4; r++) {
      float mr = fmaxf(fmaxf(s[0][r], s[1][r]), fmaxf(s[2][r], s[3][r]));
#pragma unroll
      for (int msk = 1; msk < 16; msk <<= 1) mr = fmaxf(mr, __shfl_xor(mr, msk));
      float mn = fmaxf(m_run[r], mr);
      float sum = 0.f;
#pragma unroll
      for (int t = 0; t < 4; t++) {
        float pv = __expf(s[t][r] - mn);
        p[t][r] = pv;
        sum += pv;
      }
#pragma unroll
      for (int msk = 1; msk < 16; msk <<= 1) sum += __shfl_xor(sum, msk);
      float cr = __expf(m_run[r] - mn);
      l_run[r] = l_run[r] * cr + sum;
      m_run[r] = mn;
      corr[r] = cr;
    }
#pragma unroll
    for (int t = 0; t < 4; t++)
#pragma unroll
      for (int r = 0; r < 4; r++) o[t][r] *= corr[r];

    // P -> per-wave LDS (acc layout) -> re-read as A-fragments
#pragma unroll
    for (int t = 0; t < 4; t++)
#pragma unroll
      for (int r = 0; r < 4; r++)
        Ps[w][(lg * 4 + r) * 72 + t * 16 + li] = __float2bfloat16(p[t][r]);

    s16x8 ap[2];
#pragma unroll
    for (int c = 0; c < 2; c++)
      ap[c] = load16B(&Ps[w][li * 72 + c * 32 + lg * 8]);

    // O += P @ V : B-frag from V^T rows (d = li+16t), elems = k
#pragma unroll
    for (int t = 0; t < 4; t++) {
#pragma unroll
      for (int c = 0; c < 2; c++) {
        int row = t * 16 + li;
        s16x8 bv = load16B((char*)Vts +
                           ((row * 128 + c * 64 + lg * 16) ^ ((row & 7) << 4)));
        o[t] = __builtin_amdgcn_mfma_f32_16x16x32_bf16(ap[c], bv, o[t], 0, 0, 0);
      }
    }
  }

  const int b = bh >> 4, h = bh & 15;
#pragma unroll
  for (int r = 0; r < 4; r++) {
    float inv = 1.0f / l_run[r];
#pragma unroll
    for (int t = 0; t < 4; t++) {
      size_t idx = (size_t)(b * SEQ + qrow + lg * 4 + r) * 1024 + h * 64 +
                   t * 16 + li;
      attn[idx] = __float2bfloat16(o[t][r] * inv);
    }
  }
}

extern "C" void kernel_launch(void* const* d_in, const int* in_sizes, int n_in,
                              void* d_out, int out_size, void* d_ws,
                              size_t ws_size, hipStream_t stream) {
  (void)in_sizes; (void)n_in; (void)out_size;
  const float* value = (const float*)d_in[0];
  const float* key   = (const float*)d_in[1];
  const float* query = (const float*)d_in[2];
  // d_in[3] = mask (int32 causal tril) — causality applied analytically
  const float* Wq_w = (const float*)d_in[4];
  const float* Wq_b = (const float*)d_in[5];
  const float* Wk_w = (const float*)d_in[6];
  const float* Wk_b = (const float*)d_in[7];
  const float* Wv_w = (const float*)d_in[8];
  const float* Wv_b = (const float*)d_in[9];
  // d_in[10..11] = Wr (computed-then-deleted in reference) — skipped
  const float* wo_w = (const float*)d_in[12];
  const float* wo_b = (const float*)d_in[13];

  bf16* ws = (bf16*)d_ws;
  const size_t MM = 1048576;
  bf16* WT = ws;                         // 4 transposed bf16 weights, 4*MM

  const bool fused = ws_size >= (size_t)56 * 1024 * 1024;

  k_transpose<<<dim3(16, 16, 4), 256, 0, stream>>>(Wq_w, Wk_w, Wv_w, wo_w, WT);

  if (fused) {
    bf16* qx   = ws + 4 * MM;
    bf16* kx   = ws + 8 * MM;
    bf16* vx   = ws + 12 * MM;
    bf16* qbuf = ws + 16 * MM;
    bf16* kbuf = ws + 20 * MM;
    bf16* vtbf = ws + 24 * MM;
    bf16* abuf = ws + 4 * MM;            // alias qx (dead after QKV GEMM)
    k_cvt<<<2048, 256, 0, stream>>>(query, qx);
    k_cvt<<<2048, 256, 0, stream>>>(key, kx);
    k_cvt<<<2048, 256, 0, stream>>>(value, vx);
    k_gemm_qkv<<<dim3(8, 32, 3), 256, 0, stream>>>(
        qx, kx, vx, WT, Wq_b, Wk_b, Wv_b, qbuf, kbuf, vtbf, 0);
    k_attn<<<dim3(32, 32), 256, 0, stream>>>(qbuf, kbuf, vtbf, abuf);
    k_gemm_out<<<dim3(8, 32), 256, 0, stream>>>(abuf, WT + 3 * MM, wo_b,
                                                (float*)d_out);
  } else {                               // 40 MB layout, serialized QKV
    bf16* xbuf = ws + 4 * MM;
    bf16* qbuf = ws + 8 * MM;
    bf16* kbuf = ws + 12 * MM;
    bf16* vtbf = ws + 16 * MM;
    bf16* abuf = ws + 4 * MM;            // alias xbuf (dead after V GEMM)
    k_cvt<<<2048, 256, 0, stream>>>(query, xbuf);
    k_gemm_qkv<<<dim3(8, 32, 1), 256, 0, stream>>>(
        xbuf, xbuf, xbuf, WT, Wq_b, Wk_b, Wv_b, qbuf, kbuf, vtbf, 0);
    k_cvt<<<2048, 256, 0, stream>>>(key, xbuf);
    k_gemm_qkv<<<dim3(8, 32, 1), 256, 0, stream>>>(
        xbuf, xbuf, xbuf, WT, Wq_b, Wk_b, Wv_b, qbuf, kbuf, vtbf, 1);
    k_cvt<<<2048, 256, 0, stream>>>(value, xbuf);
    k_gemm_qkv<<<dim3(8, 32, 1), 256, 0, stream>>>(
        xbuf, xbuf, xbuf, WT, Wq_b, Wk_b, Wv_b, qbuf, kbuf, vtbf, 2);
    k_attn<<<dim3(32, 32), 256, 0, stream>>>(qbuf, kbuf, vtbf, abuf);
    k_gemm_out<<<dim3(8, 32), 256, 0, stream>>>(abuf, WT + 3 * MM, wo_b,
                                                (float*)d_out);
  }
}

// Round 7
// 172.957 us; speedup vs baseline: 1.5358x; 1.1263x over previous
//
#include <hip/hip_runtime.h>
#include <hip/hip_bf16.h>

typedef __hip_bfloat16 bf16;
typedef __attribute__((ext_vector_type(4))) float f32x4;
typedef __attribute__((ext_vector_type(8))) short s16x8;

#define DEVINL __device__ __forceinline__

DEVINL s16x8 load16B(const void* p) {
  s16x8 v;
  __builtin_memcpy(&v, __builtin_assume_aligned(p, 16), 16);
  return v;
}
DEVINL void store16B(void* p, s16x8 v) {
  __builtin_memcpy(__builtin_assume_aligned(p, 16), &v, 16);
}
// load 8 consecutive f32, downcast to 8 bf16 packed in s16x8
DEVINL s16x8 cvt8(const float* p) {
  f32x4 a, b;
  __builtin_memcpy(&a, __builtin_assume_aligned(p, 16), 16);
  __builtin_memcpy(&b, __builtin_assume_aligned(p + 4, 16), 16);
  union { s16x8 v; bf16 h[8]; } u;
#pragma unroll
  for (int i = 0; i < 4; i++) {
    u.h[i] = __float2bfloat16(a[i]);
    u.h[4 + i] = __float2bfloat16(b[i]);
  }
  return u.v;
}
// async global->LDS 16B (m97 pattern): LDS dest = wave-uniform base + lane*16
DEVINL void gload_lds16(const bf16* g, bf16* l) {
  __builtin_amdgcn_global_load_lds(
      (__attribute__((address_space(1))) void*)(void*)const_cast<bf16*>(g),
      (__attribute__((address_space(3))) void*)l, 16, 0, 0);
}

static constexpr int SEQ = 2048;   // L
// DX = 1024, H = 16, Dh = 64, B = 2 hard-coded below.

// ------ weight transpose + downcast: dst[n*1024+k] = bf16(src[k*1024+n]) ---
__global__ __launch_bounds__(256) void k_transpose(
    const float* __restrict__ Wq, const float* __restrict__ Wk,
    const float* __restrict__ Wv, const float* __restrict__ Wo,
    bf16* __restrict__ dst) {
  __shared__ float t[64][65];
  const float* src = blockIdx.z == 0 ? Wq : blockIdx.z == 1 ? Wk
                   : blockIdx.z == 2 ? Wv : Wo;
  bf16* out = dst + (size_t)blockIdx.z * 1024 * 1024;
  const int r0 = blockIdx.y * 64, c0 = blockIdx.x * 64;
#pragma unroll
  for (int i = 0; i < 16; i++) {
    int e = i * 256 + threadIdx.x;
    int r = e >> 6, c = e & 63;
    t[r][c] = src[(size_t)(r0 + r) * 1024 + c0 + c];
  }
  __syncthreads();
#pragma unroll
  for (int i = 0; i < 16; i++) {
    int e = i * 256 + threadIdx.x;
    int r = e >> 6, c = e & 63;
    out[(size_t)(c0 + r) * 1024 + r0 + c] = __float2bfloat16(t[c][r]);
  }
}

// ------------------- f32 -> bf16 elementwise (4.19M elems) -----------------
__global__ __launch_bounds__(256) void k_cvt(const float* __restrict__ src,
                                             bf16* __restrict__ dst) {
  size_t i = ((size_t)blockIdx.x * 256 + threadIdx.x) * 8;
  store16B(dst + i, cvt8(src + i));
}

// -------- shared GEMM core: C = X[4096,1024] @ WT^T + bias ----------------
// X, WT bf16 row-major [*,1024]; staging via global_load_lds dwordx4 (m97).
// mode 0: dst bf16 per-head token-major [bh][l][64], value scaled (Q/K)
// mode 1: dst bf16 per-head d-major     [bh][64][l]  (V^T)
// mode 2: dst f32 natural               [m][1024]    (final out)
DEVINL void gemm_core(const bf16* __restrict__ X, const bf16* __restrict__ WT,
                      const float* __restrict__ bias, void* __restrict__ dstv,
                      const int mode, const float scale, const int m0,
                      const int n0) {
  __shared__ alignas(16) bf16 As[128 * 32];
  __shared__ alignas(16) bf16 Bs[128 * 32];
  const int tid = threadIdx.x;
  const int w = tid >> 6, lane = tid & 63, lg = lane >> 4, li = lane & 15;
  const int wm = w >> 1, wn = w & 1;

  f32x4 acc[4][4] = {};

  for (int kt = 0; kt < 32; ++kt) {
    const int k0 = kt * 32;
#pragma unroll
    for (int j = 0; j < 2; j++) {
      const int cb = (j * 4 + w) * 64;       // wave-uniform chunk base
      const int c = cb + lane;               // 16B chunk: row=c>>2, k=(c&3)*8
      const int r = c >> 2, kk = (c & 3) * 8;
      gload_lds16(X + (size_t)(m0 + r) * 1024 + k0 + kk, As + cb * 8);
      gload_lds16(WT + (size_t)(n0 + r) * 1024 + k0 + kk, Bs + cb * 8);
    }
    __syncthreads();   // compiler drains vmcnt before s_barrier (m97)
    s16x8 af[4], bfv[4];
#pragma unroll
    for (int i = 0; i < 4; i++)
      af[i] = load16B((char*)As + (wm * 64 + i * 16 + li) * 64 + lg * 16);
#pragma unroll
    for (int j = 0; j < 4; j++)
      bfv[j] = load16B((char*)Bs + (wn * 64 + j * 16 + li) * 64 + lg * 16);
#pragma unroll
    for (int i = 0; i < 4; i++)
#pragma unroll
      for (int j = 0; j < 4; j++)
        acc[i][j] = __builtin_amdgcn_mfma_f32_16x16x32_bf16(af[i], bfv[j],
                                                            acc[i][j], 0, 0, 0);
    __syncthreads();   // all waves done reading before next overwrite
  }

  // C/D layout: lane reg r -> row (lane>>4)*4+r, col lane&15 (m89/m91)
#pragma unroll
  for (int j = 0; j < 4; j++) {
    const int n = n0 + wn * 64 + j * 16 + li;
    const float bv = bias[n];
#pragma unroll
    for (int i = 0; i < 4; i++) {
      const int mrow = m0 + wm * 64 + i * 16 + lg * 4;
      f32x4 a = acc[i][j];
      if (mode == 2) {
        float* dst = (float*)dstv;
#pragma unroll
        for (int r = 0; r < 4; r++)
          dst[(size_t)(mrow + r) * 1024 + n] = a[r] + bv;
      } else if (mode == 0) {
        bf16* dst = (bf16*)dstv;
#pragma unroll
        for (int r = 0; r < 4; r++) {
          int m = mrow + r;   // b=m>>11, l=m&2047, h=n>>6, d=n&63
          size_t idx =
              ((size_t)((m >> 11) * 16 + (n >> 6)) * SEQ + (m & 2047)) * 64 +
              (n & 63);
          dst[idx] = __float2bfloat16((a[r] + bv) * scale);
        }
      } else {  // mode 1: V^T, 4 consecutive tokens same d -> one 8B store
        bf16* dst = (bf16*)dstv;
        size_t base =
            ((size_t)((mrow >> 11) * 16 + (n >> 6)) * 64 + (n & 63)) * SEQ +
            (mrow & 2047);
        bf16 tmp[4];
#pragma unroll
        for (int r = 0; r < 4; r++) tmp[r] = __float2bfloat16(a[r] + bv);
        __builtin_memcpy(__builtin_assume_aligned(dst + base, 8), tmp, 8);
      }
    }
  }
}

// fused Q/K/V projections: z selects input/weight/bias/dst/mode/scale
__global__ __launch_bounds__(256) void k_gemm_qkv(
    const bf16* __restrict__ qx, const bf16* __restrict__ kx,
    const bf16* __restrict__ vx, const bf16* __restrict__ WTbase,
    const float* __restrict__ qb, const float* __restrict__ kb,
    const float* __restrict__ vb, bf16* __restrict__ qo,
    bf16* __restrict__ ko, bf16* __restrict__ vto, int zbase) {
  const int z = zbase + blockIdx.z;
  const bf16* X = z == 0 ? qx : z == 1 ? kx : vx;
  const bf16* WT = WTbase + (size_t)z * 1048576;
  const float* bias = z == 0 ? qb : z == 1 ? kb : vb;
  void* dst = z == 0 ? (void*)qo : z == 1 ? (void*)ko : (void*)vto;
  gemm_core(X, WT, bias, dst, z == 2 ? 1 : 0, z == 0 ? 0.03125f : 1.0f,
            blockIdx.y * 128, blockIdx.x * 128);
}

__global__ __launch_bounds__(256) void k_gemm_out(
    const bf16* __restrict__ X, const bf16* __restrict__ WT,
    const float* __restrict__ bias, float* __restrict__ out) {
  gemm_core(X, WT, bias, out, 2, 1.0f, blockIdx.y * 128, blockIdx.x * 128);
}

// ------------------------- causal flash attention --------------------------
// grid (32,32), 256 thr = 4 waves x 16 q-rows, KBLK=64, longest-first.
// SWAPPED QK^T: S^T = mfma(K,Q) -> lane (lg,li) holds 16 scores of q-row li
// (k = t*16+lg*4+r). Softmax = in-lane tree + 2 shuffles for all 16 rows.
// Double-buffered K/V LDS -> 1 barrier/iter. Q pre-scaled by 1/32.
__global__ __launch_bounds__(256) void k_attn(
    const bf16* __restrict__ qb, const bf16* __restrict__ kb,
    const bf16* __restrict__ vtb, bf16* __restrict__ attn) {
  __shared__ alignas(16) bf16 Ks[2][64 * 64];   // [buf][k][d], XOR-swizzled
  __shared__ alignas(16) bf16 Vts[2][64 * 64];  // [buf][d][k], XOR-swizzled
  __shared__ alignas(16) bf16 Ps[4][16 * 72];   // per-wave P [q=li][k], +8 pad
  const int tid = threadIdx.x;
  const int w = tid >> 6, lane = tid & 63, lg = lane >> 4, li = lane & 15;
  const int bh = blockIdx.y;
  const int qblk = 31 - blockIdx.x;             // longest blocks first
  const int qrow = qblk * 64 + w * 16;
  const bf16* qh = qb + (size_t)bh * SEQ * 64;
  const bf16* kh = kb + (size_t)bh * SEQ * 64;
  const bf16* vth = vtb + (size_t)bh * 64 * SEQ;

  s16x8 aq[2];  // Q fragments (B-operand now) held in registers all kernel
#pragma unroll
  for (int c = 0; c < 2; c++)
    aq[c] = load16B(qh + (size_t)(qrow + li) * 64 + c * 32 + lg * 8);

  f32x4 o[4] = {};
  float m_run = -1e38f;   // per-lane: stats of q-row (qrow + li)
  float l_run = 0.f;

  // staging helpers (register prefetch -> swizzled LDS write)
  const int c0s = tid, c1s = 256 + tid;
  const int by0 = (c0s * 16) ^ (((c0s >> 3) & 7) << 4);
  const int by1 = (c1s * 16) ^ (((c1s >> 3) & 7) << 4);
  const int d0 = c0s >> 3, kk0 = (c0s & 7) * 8;
  const int d1 = c1s >> 3, kk1 = (c1s & 7) * 8;

  s16x8 rk[2], rv[2];
  // prologue: tile 0 -> regs -> buf0; prefetch tile 1 -> regs
  rk[0] = load16B(kh + (size_t)c0s * 8);
  rk[1] = load16B(kh + (size_t)c1s * 8);
  rv[0] = load16B(vth + (size_t)d0 * SEQ + kk0);
  rv[1] = load16B(vth + (size_t)d1 * SEQ + kk1);
  store16B((char*)Ks[0] + by0, rk[0]);
  store16B((char*)Ks[0] + by1, rk[1]);
  store16B((char*)Vts[0] + by0, rv[0]);
  store16B((char*)Vts[0] + by1, rv[1]);
  if (qblk >= 1) {
    rk[0] = load16B(kh + (size_t)64 * 64 + c0s * 8);
    rk[1] = load16B(kh + (size_t)64 * 64 + c1s * 8);
    rv[0] = load16B(vth + (size_t)d0 * SEQ + 64 + kk0);
    rv[1] = load16B(vth + (size_t)d1 * SEQ + 64 + kk1);
  }
  __syncthreads();

  for (int kbk = 0; kbk <= qblk; ++kbk) {
    const int cur = kbk & 1;
    if (kbk < qblk) {                 // write tile kbk+1 to alt buffer
      store16B((char*)Ks[cur ^ 1] + by0, rk[0]);
      store16B((char*)Ks[cur ^ 1] + by1, rk[1]);
      store16B((char*)Vts[cur ^ 1] + by0, rv[0]);
      store16B((char*)Vts[cur ^ 1] + by1, rv[1]);
      if (kbk + 2 <= qblk) {          // issue loads for tile kbk+2
        const int kn = (kbk + 2) * 64;
        rk[0] = load16B(kh + (size_t)kn * 64 + c0s * 8);
        rk[1] = load16B(kh + (size_t)kn * 64 + c1s * 8);
        rv[0] = load16B(vth + (size_t)d0 * SEQ + kn + kk0);
        rv[1] = load16B(vth + (size_t)d1 * SEQ + kn + kk1);
      }
    }

    // S^T = K Q^T : A-frag = K rows, B-frag = Q rows
    // s[t][r] = S[q = qrow+li][k = kbk*64 + t*16 + lg*4 + r]
    f32x4 s[4];
    __builtin_amdgcn_s_setprio(1);
#pragma unroll
    for (int t = 0; t < 4; t++) {
      f32x4 z = {};
#pragma unroll
      for (int c = 0; c < 2; c++) {
        int row = t * 16 + li;
        s16x8 ak = load16B((char*)Ks[cur] +
                           ((row * 128 + c * 64 + lg * 16) ^ ((row & 7) << 4)));
        z = __builtin_amdgcn_mfma_f32_16x16x32_bf16(ak, aq[c], z, 0, 0, 0);
      }
      s[t] = z;
    }
    __builtin_amdgcn_s_setprio(0);

    if (kbk == qblk) {  // diagonal block: per-element causal mask
      const int kb0 = kbk * 64 + lg * 4;
      const int qg = qrow + li;
#pragma unroll
      for (int t = 0; t < 4; t++)
#pragma unroll
        for (int r = 0; r < 4; r++)
          if (kb0 + t * 16 + r > qg) s[t][r] = -1e30f;
    }

    // softmax for all 16 q-rows at once: in-lane tree + xor16/xor32
    f32x4 mm = s[0];
#pragma unroll
    for (int t = 1; t < 4; t++)
#pragma unroll
      for (int r = 0; r < 4; r++) mm[r] = fmaxf(mm[r], s[t][r]);
    float mr = fmaxf(fmaxf(mm[0], mm[1]), fmaxf(mm[2], mm[3]));
    mr = fmaxf(mr, __shfl_xor(mr, 16));
    mr = fmaxf(mr, __shfl_xor(mr, 32));
    const float mn = fmaxf(m_run, mr);

    float p[4][4];
    float sum = 0.f;
#pragma unroll
    for (int t = 0; t < 4; t++)
#pragma unroll
      for (int r = 0; r < 4; r++) {
        float pv = __expf(s[t][r] - mn);
        p[t][r] = pv;
        sum += pv;
      }
    sum += __shfl_xor(sum, 16);
    sum += __shfl_xor(sum, 32);
    const float cr = __expf(m_run - mn);
    l_run = l_run * cr + sum;
    m_run = mn;

    // P -> per-wave LDS in [q=li][k] layout (8B packed stores)
#pragma unroll
    for (int t = 0; t < 4; t++) {
      bf16 tmp[4];
#pragma unroll
      for (int r = 0; r < 4; r++) tmp[r] = __float2bfloat16(p[t][r]);
      __builtin_memcpy(
          __builtin_assume_aligned(&Ps[w][li * 72 + t * 16 + lg * 4], 8), tmp,
          8);
    }

    // rescale O: row (qrow + lg*4 + r) stats live at lane li = lg*4+r
    const int sb = (lane & 48);
    float crr[4];
#pragma unroll
    for (int r = 0; r < 4; r++) crr[r] = __shfl(cr, sb + (sb >> 2) + r);
#pragma unroll
    for (int t = 0; t < 4; t++)
#pragma unroll
      for (int r = 0; r < 4; r++) o[t][r] *= crr[r];

    s16x8 ap[2];
#pragma unroll
    for (int c = 0; c < 2; c++)
      ap[c] = load16B(&Ps[w][li * 72 + c * 32 + lg * 8]);

    // O += P @ V : B-frag from V^T rows (d = t*16+li)
    __builtin_amdgcn_s_setprio(1);
#pragma unroll
    for (int t = 0; t < 4; t++) {
#pragma unroll
      for (int c = 0; c < 2; c++) {
        int row = t * 16 + li;
        s16x8 bv = load16B((char*)Vts[cur] +
                           ((row * 128 + c * 64 + lg * 16) ^ ((row & 7) << 4)));
        o[t] = __builtin_amdgcn_mfma_f32_16x16x32_bf16(ap[c], bv, o[t], 0, 0, 0);
      }
    }
    __builtin_amdgcn_s_setprio(0);
    __syncthreads();
  }

  const int b = bh >> 4, h = bh & 15;
  const float inv = 1.0f / l_run;
  const int sb = (lane & 48);
  float invr[4];
#pragma unroll
  for (int r = 0; r < 4; r++) invr[r] = __shfl(inv, sb + (sb >> 2) + r);
#pragma unroll
  for (int r = 0; r < 4; r++)
#pragma unroll
    for (int t = 0; t < 4; t++) {
      size_t idx = (size_t)(b * SEQ + qrow + lg * 4 + r) * 1024 + h * 64 +
                   t * 16 + li;
      attn[idx] = __float2bfloat16(o[t][r] * invr[r]);
    }
}

extern "C" void kernel_launch(void* const* d_in, const int* in_sizes, int n_in,
                              void* d_out, int out_size, void* d_ws,
                              size_t ws_size, hipStream_t stream) {
  (void)in_sizes; (void)n_in; (void)out_size;
  const float* value = (const float*)d_in[0];
  const float* key   = (const float*)d_in[1];
  const float* query = (const float*)d_in[2];
  // d_in[3] = mask (int32 causal tril) — causality applied analytically
  const float* Wq_w = (const float*)d_in[4];
  const float* Wq_b = (const float*)d_in[5];
  const float* Wk_w = (const float*)d_in[6];
  const float* Wk_b = (const float*)d_in[7];
  const float* Wv_w = (const float*)d_in[8];
  const float* Wv_b = (const float*)d_in[9];
  // d_in[10..11] = Wr (computed-then-deleted in reference) — skipped
  const float* wo_w = (const float*)d_in[12];
  const float* wo_b = (const float*)d_in[13];

  bf16* ws = (bf16*)d_ws;
  const size_t MM = 1048576;
  bf16* WT = ws;                         // 4 transposed bf16 weights, 4*MM

  const bool fused = ws_size >= (size_t)56 * 1024 * 1024;

  k_transpose<<<dim3(16, 16, 4), 256, 0, stream>>>(Wq_w, Wk_w, Wv_w, wo_w, WT);

  if (fused) {
    bf16* qx   = ws + 4 * MM;
    bf16* kx   = ws + 8 * MM;
    bf16* vx   = ws + 12 * MM;
    bf16* qbuf = ws + 16 * MM;
    bf16* kbuf = ws + 20 * MM;
    bf16* vtbf = ws + 24 * MM;
    bf16* abuf = ws + 4 * MM;            // alias qx (dead after QKV GEMM)
    k_cvt<<<2048, 256, 0, stream>>>(query, qx);
    k_cvt<<<2048, 256, 0, stream>>>(key, kx);
    k_cvt<<<2048, 256, 0, stream>>>(value, vx);
    k_gemm_qkv<<<dim3(8, 32, 3), 256, 0, stream>>>(
        qx, kx, vx, WT, Wq_b, Wk_b, Wv_b, qbuf, kbuf, vtbf, 0);
    k_attn<<<dim3(32, 32), 256, 0, stream>>>(qbuf, kbuf, vtbf, abuf);
    k_gemm_out<<<dim3(8, 32), 256, 0, stream>>>(abuf, WT + 3 * MM, wo_b,
                                                (float*)d_out);
  } else {                               // 40 MB layout, serialized QKV
    bf16* xbuf = ws + 4 * MM;
    bf16* qbuf = ws + 8 * MM;
    bf16* kbuf = ws + 12 * MM;
    bf16* vtbf = ws + 16 * MM;
    bf16* abuf = ws + 4 * MM;            // alias xbuf (dead after V GEMM)
    k_cvt<<<2048, 256, 0, stream>>>(query, xbuf);
    k_gemm_qkv<<<dim3(8, 32, 1), 256, 0, stream>>>(
        xbuf, xbuf, xbuf, WT, Wq_b, Wk_b, Wv_b, qbuf, kbuf, vtbf, 0);
    k_cvt<<<2048, 256, 0, stream>>>(key, xbuf);
    k_gemm_qkv<<<dim3(8, 32, 1), 256, 0, stream>>>(
        xbuf, xbuf, xbuf, WT, Wq_b, Wk_b, Wv_b, qbuf, kbuf, vtbf, 1);
    k_cvt<<<2048, 256, 0, stream>>>(value, xbuf);
    k_gemm_qkv<<<dim3(8, 32, 1), 256, 0, stream>>>(
        xbuf, xbuf, xbuf, WT, Wq_b, Wk_b, Wv_b, qbuf, kbuf, vtbf, 2);
    k_attn<<<dim3(32, 32), 256, 0, stream>>>(qbuf, kbuf, vtbf, abuf);
    k_gemm_out<<<dim3(8, 32), 256, 0, stream>>>(abuf, WT + 3 * MM, wo_b,
                                                (float*)d_out);
  }
}

// Round 9
// 140.247 us; speedup vs baseline: 1.8940x; 1.2332x over previous
//
#include <hip/hip_runtime.h>
#include <hip/hip_bf16.h>
#include <type_traits>

typedef __hip_bfloat16 bf16;
typedef __attribute__((ext_vector_type(4))) float f32x4;
typedef __attribute__((ext_vector_type(8))) short s16x8;

#define DEVINL __device__ __forceinline__

DEVINL s16x8 load16B(const void* p) {
  s16x8 v;
  __builtin_memcpy(&v, __builtin_assume_aligned(p, 16), 16);
  return v;
}
DEVINL void store16B(void* p, s16x8 v) {
  __builtin_memcpy(__builtin_assume_aligned(p, 16), &v, 16);
}
// load 8 consecutive f32, downcast to 8 bf16 packed in s16x8
DEVINL s16x8 cvt8(const float* p) {
  f32x4 a, b;
  __builtin_memcpy(&a, __builtin_assume_aligned(p, 16), 16);
  __builtin_memcpy(&b, __builtin_assume_aligned(p + 4, 16), 16);
  union { s16x8 v; bf16 h[8]; } u;
#pragma unroll
  for (int i = 0; i < 4; i++) {
    u.h[i] = __float2bfloat16(a[i]);
    u.h[4 + i] = __float2bfloat16(b[i]);
  }
  return u.v;
}
// async global->LDS 16B (m97 pattern): LDS dest = wave-uniform base + lane*16
DEVINL void gload_lds16(const bf16* g, bf16* l) {
  __builtin_amdgcn_global_load_lds(
      (__attribute__((address_space(1))) void*)(void*)const_cast<bf16*>(g),
      (__attribute__((address_space(3))) void*)l, 16, 0, 0);
}

static constexpr int SEQ = 2048;   // L
// DX = 1024, H = 16, Dh = 64, B = 2 hard-coded below.

// ------ weight transpose + downcast: dst[n*1024+k] = bf16(src[k*1024+n]) ---
__global__ __launch_bounds__(256) void k_transpose(
    const float* __restrict__ Wq, const float* __restrict__ Wk,
    const float* __restrict__ Wv, const float* __restrict__ Wo,
    bf16* __restrict__ dst) {
  __shared__ float t[64][65];
  const float* src = blockIdx.z == 0 ? Wq : blockIdx.z == 1 ? Wk
                   : blockIdx.z == 2 ? Wv : Wo;
  bf16* out = dst + (size_t)blockIdx.z * 1024 * 1024;
  const int r0 = blockIdx.y * 64, c0 = blockIdx.x * 64;
#pragma unroll
  for (int i = 0; i < 16; i++) {
    int e = i * 256 + threadIdx.x;
    int r = e >> 6, c = e & 63;
    t[r][c] = src[(size_t)(r0 + r) * 1024 + c0 + c];
  }
  __syncthreads();
#pragma unroll
  for (int i = 0; i < 16; i++) {
    int e = i * 256 + threadIdx.x;
    int r = e >> 6, c = e & 63;
    out[(size_t)(c0 + r) * 1024 + r0 + c] = __float2bfloat16(t[c][r]);
  }
}

// -------- shared GEMM core: C = X[4096,1024] @ WT^T + bias ----------------
// WT bf16 [n][k] staged via global_load_lds; X either bf16 (gload_lds) or
// f32 (reg-stage + cvt + ds_write — fuses the downcast into the GEMM).
// mode 0: dst bf16 per-head token-major [bh][l][64], scaled (Q)  / K
// mode 1: dst bf16 per-head d-major     [bh][64][l]  (V^T)
// mode 2: dst f32 natural               [m][1024]    (final out)
template <typename XT>
DEVINL void gemm_core(const XT* __restrict__ X, const bf16* __restrict__ WT,
                      const float* __restrict__ bias, void* __restrict__ dstv,
                      const int mode, const float scale, const int m0,
                      const int n0) {
  __shared__ alignas(16) bf16 As[128 * 32];
  __shared__ alignas(16) bf16 Bs[128 * 32];
  const int tid = threadIdx.x;
  const int w = tid >> 6, lane = tid & 63, lg = lane >> 4, li = lane & 15;
  const int wm = w >> 1, wn = w & 1;

  f32x4 acc[4][4] = {};

  for (int kt = 0; kt < 32; ++kt) {
    const int k0 = kt * 32;
#pragma unroll
    for (int j = 0; j < 2; j++) {
      const int cb = (j * 4 + w) * 64;       // wave-uniform chunk base
      const int c = cb + lane;               // 16B chunk: row=c>>2, k=(c&3)*8
      const int r = c >> 2, kk = (c & 3) * 8;
      gload_lds16(WT + (size_t)(n0 + r) * 1024 + k0 + kk, Bs + cb * 8);
      if constexpr (std::is_same_v<XT, bf16>)
        gload_lds16(X + (size_t)(m0 + r) * 1024 + k0 + kk, As + cb * 8);
    }
    if constexpr (std::is_same_v<XT, float>) {  // fused cvt staging for A
#pragma unroll
      for (int j = 0; j < 2; j++) {
        const int c = j * 256 + tid;
        const int r = c >> 2, kk = (c & 3) * 8;
        s16x8 a = cvt8(X + (size_t)(m0 + r) * 1024 + k0 + kk);
        store16B((char*)As + c * 16, a);
      }
    }
    __syncthreads();   // drains vmcnt+lgkmcnt before s_barrier (m97)
    s16x8 af[4], bfv[4];
#pragma unroll
    for (int i = 0; i < 4; i++)
      af[i] = load16B((char*)As + (wm * 64 + i * 16 + li) * 64 + lg * 16);
#pragma unroll
    for (int j = 0; j < 4; j++)
      bfv[j] = load16B((char*)Bs + (wn * 64 + j * 16 + li) * 64 + lg * 16);
#pragma unroll
    for (int i = 0; i < 4; i++)
#pragma unroll
      for (int j = 0; j < 4; j++)
        acc[i][j] = __builtin_amdgcn_mfma_f32_16x16x32_bf16(af[i], bfv[j],
                                                            acc[i][j], 0, 0, 0);
    __syncthreads();   // all waves done reading before next overwrite
  }

  // C/D layout: lane reg r -> row (lane>>4)*4+r, col lane&15 (m89/m91)
#pragma unroll
  for (int j = 0; j < 4; j++) {
    const int n = n0 + wn * 64 + j * 16 + li;
    const float bv = bias[n];
#pragma unroll
    for (int i = 0; i < 4; i++) {
      const int mrow = m0 + wm * 64 + i * 16 + lg * 4;
      f32x4 a = acc[i][j];
      if (mode == 2) {
        float* dst = (float*)dstv;
#pragma unroll
        for (int r = 0; r < 4; r++)
          dst[(size_t)(mrow + r) * 1024 + n] = a[r] + bv;
      } else if (mode == 0) {
        bf16* dst = (bf16*)dstv;
#pragma unroll
        for (int r = 0; r < 4; r++) {
          int m = mrow + r;   // b=m>>11, l=m&2047, h=n>>6, d=n&63
          size_t idx =
              ((size_t)((m >> 11) * 16 + (n >> 6)) * SEQ + (m & 2047)) * 64 +
              (n & 63);
          dst[idx] = __float2bfloat16((a[r] + bv) * scale);
        }
      } else {  // mode 1: V^T, 4 consecutive tokens same d -> one 8B store
        bf16* dst = (bf16*)dstv;
        size_t base =
            ((size_t)((mrow >> 11) * 16 + (n >> 6)) * 64 + (n & 63)) * SEQ +
            (mrow & 2047);
        bf16 tmp[4];
#pragma unroll
        for (int r = 0; r < 4; r++) tmp[r] = __float2bfloat16(a[r] + bv);
        __builtin_memcpy(__builtin_assume_aligned(dst + base, 8), tmp, 8);
      }
    }
  }
}

// fused Q/K/V projections from f32 inputs (cvt fused into staging)
__global__ __launch_bounds__(256) void k_gemm_qkv(
    const float* __restrict__ qx, const float* __restrict__ kx,
    const float* __restrict__ vx, const bf16* __restrict__ WTbase,
    const float* __restrict__ qb, const float* __restrict__ kb,
    const float* __restrict__ vb, bf16* __restrict__ qo,
    bf16* __restrict__ ko, bf16* __restrict__ vto) {
  const int z = blockIdx.z;
  const float* X = z == 0 ? qx : z == 1 ? kx : vx;
  const bf16* WT = WTbase + (size_t)z * 1048576;
  const float* bias = z == 0 ? qb : z == 1 ? kb : vb;
  void* dst = z == 0 ? (void*)qo : z == 1 ? (void*)ko : (void*)vto;
  gemm_core<float>(X, WT, bias, dst, z == 2 ? 1 : 0, z == 0 ? 0.03125f : 1.0f,
                   blockIdx.y * 128, blockIdx.x * 128);
}

__global__ __launch_bounds__(256) void k_gemm_out(
    const bf16* __restrict__ X, const bf16* __restrict__ WT,
    const float* __restrict__ bias, float* __restrict__ out) {
  gemm_core<bf16>(X, WT, bias, out, 2, 1.0f, blockIdx.y * 128,
                  blockIdx.x * 128);
}

// ------------------------- causal flash attention --------------------------
// grid (x=bh 32, y=qy 32), qblk = 31-qy. bh in x => per-CU qblk mix
// {31-q0,23-q0,15-q0,7-q0} (balanced, heaviest dispatched first) and all
// blocks of one bh share an XCD (id%8 = bh%8) for K/V L2 locality.
// SWAPPED QK^T: S^T = mfma(K,Q) -> lane (lg,li) holds 16 scores of q-row li.
// Double-buffered K/V LDS, 1 barrier/iter. Q pre-scaled by 1/32.
__global__ __launch_bounds__(256) void k_attn(
    const bf16* __restrict__ qb, const bf16* __restrict__ kb,
    const bf16* __restrict__ vtb, bf16* __restrict__ attn) {
  __shared__ alignas(16) bf16 Ks[2][64 * 64];   // [buf][k][d], XOR-swizzled
  __shared__ alignas(16) bf16 Vts[2][64 * 64];  // [buf][d][k], XOR-swizzled
  __shared__ alignas(16) bf16 Ps[4][16 * 72];   // per-wave P [q=li][k], +8 pad
  const int tid = threadIdx.x;
  const int w = tid >> 6, lane = tid & 63, lg = lane >> 4, li = lane & 15;
  const int bh = blockIdx.x;
  const int qblk = 31 - blockIdx.y;             // heaviest first
  const int qrow = qblk * 64 + w * 16;
  const bf16* qh = qb + (size_t)bh * SEQ * 64;
  const bf16* kh = kb + (size_t)bh * SEQ * 64;
  const bf16* vth = vtb + (size_t)bh * 64 * SEQ;

  s16x8 aq[2];  // Q fragments (B-operand now) held in registers all kernel
#pragma unroll
  for (int c = 0; c < 2; c++)
    aq[c] = load16B(qh + (size_t)(qrow + li) * 64 + c * 32 + lg * 8);

  f32x4 o[4] = {};
  float m_run = -1e38f;   // per-lane: stats of q-row (qrow + li)
  float l_run = 0.f;

  // staging helpers (register prefetch -> swizzled LDS write)
  const int c0s = tid, c1s = 256 + tid;
  const int by0 = (c0s * 16) ^ (((c0s >> 3) & 7) << 4);
  const int by1 = (c1s * 16) ^ (((c1s >> 3) & 7) << 4);
  const int d0 = c0s >> 3, kk0 = (c0s & 7) * 8;
  const int d1 = c1s >> 3, kk1 = (c1s & 7) * 8;

  s16x8 rk[2], rv[2];
  // prologue: tile 0 -> regs -> buf0; prefetch tile 1 -> regs
  rk[0] = load16B(kh + (size_t)c0s * 8);
  rk[1] = load16B(kh + (size_t)c1s * 8);
  rv[0] = load16B(vth + (size_t)d0 * SEQ + kk0);
  rv[1] = load16B(vth + (size_t)d1 * SEQ + kk1);
  store16B((char*)Ks[0] + by0, rk[0]);
  store16B((char*)Ks[0] + by1, rk[1]);
  store16B((char*)Vts[0] + by0, rv[0]);
  store16B((char*)Vts[0] + by1, rv[1]);
  if (qblk >= 1) {
    rk[0] = load16B(kh + (size_t)64 * 64 + c0s * 8);
    rk[1] = load16B(kh + (size_t)64 * 64 + c1s * 8);
    rv[0] = load16B(vth + (size_t)d0 * SEQ + 64 + kk0);
    rv[1] = load16B(vth + (size_t)d1 * SEQ + 64 + kk1);
  }
  __syncthreads();

  for (int kbk = 0; kbk <= qblk; ++kbk) {
    const int cur = kbk & 1;
    if (kbk < qblk) {                 // write tile kbk+1 to alt buffer
      store16B((char*)Ks[cur ^ 1] + by0, rk[0]);
      store16B((char*)Ks[cur ^ 1] + by1, rk[1]);
      store16B((char*)Vts[cur ^ 1] + by0, rv[0]);
      store16B((char*)Vts[cur ^ 1] + by1, rv[1]);
      if (kbk + 2 <= qblk) {          // issue loads for tile kbk+2
        const int kn = (kbk + 2) * 64;
        rk[0] = load16B(kh + (size_t)kn * 64 + c0s * 8);
        rk[1] = load16B(kh + (size_t)kn * 64 + c1s * 8);
        rv[0] = load16B(vth + (size_t)d0 * SEQ + kn + kk0);
        rv[1] = load16B(vth + (size_t)d1 * SEQ + kn + kk1);
      }
    }

    // S^T = K Q^T : A-frag = K rows, B-frag = Q rows
    // s[t][r] = S[q = qrow+li][k = kbk*64 + t*16 + lg*4 + r]
    f32x4 s[4];
    __builtin_amdgcn_s_setprio(1);
#pragma unroll
    for (int t = 0; t < 4; t++) {
      f32x4 z = {};
#pragma unroll
      for (int c = 0; c < 2; c++) {
        int row = t * 16 + li;
        s16x8 ak = load16B((char*)Ks[cur] +
                           ((row * 128 + c * 64 + lg * 16) ^ ((row & 7) << 4)));
        z = __builtin_amdgcn_mfma_f32_16x16x32_bf16(ak, aq[c], z, 0, 0, 0);
      }
      s[t] = z;
    }
    __builtin_amdgcn_s_setprio(0);

    if (kbk == qblk) {  // diagonal block: per-element causal mask
      const int kb0 = kbk * 64 + lg * 4;
      const int qg = qrow + li;
#pragma unroll
      for (int t = 0; t < 4; t++)
#pragma unroll
        for (int r = 0; r < 4; r++)
          if (kb0 + t * 16 + r > qg) s[t][r] = -1e30f;
    }

    // softmax for all 16 q-rows at once: in-lane tree + xor16/xor32
    f32x4 mm = s[0];
#pragma unroll
    for (int t = 1; t < 4; t++)
#pragma unroll
      for (int r = 0; r < 4; r++) mm[r] = fmaxf(mm[r], s[t][r]);
    float mr = fmaxf(fmaxf(mm[0], mm[1]), fmaxf(mm[2], mm[3]));
    mr = fmaxf(mr, __shfl_xor(mr, 16));
    mr = fmaxf(mr, __shfl_xor(mr, 32));
    const float mn = fmaxf(m_run, mr);

    float p[4][4];
    float sum = 0.f;
#pragma unroll
    for (int t = 0; t < 4; t++)
#pragma unroll
      for (int r = 0; r < 4; r++) {
        float pv = __expf(s[t][r] - mn);
        p[t][r] = pv;
        sum += pv;
      }
    sum += __shfl_xor(sum, 16);
    sum += __shfl_xor(sum, 32);
    const float cr = __expf(m_run - mn);
    l_run = l_run * cr + sum;
    m_run = mn;

    // P -> per-wave LDS in [q=li][k] layout (8B packed stores)
#pragma unroll
    for (int t = 0; t < 4; t++) {
      bf16 tmp[4];
#pragma unroll
      for (int r = 0; r < 4; r++) tmp[r] = __float2bfloat16(p[t][r]);
      __builtin_memcpy(
          __builtin_assume_aligned(&Ps[w][li * 72 + t * 16 + lg * 4], 8), tmp,
          8);
    }

    // rescale O: row (qrow + lg*4 + r) stats live at lane li = lg*4+r
    const int sb = (lane & 48);
    float crr[4];
#pragma unroll
    for (int r = 0; r < 4; r++) crr[r] = __shfl(cr, sb + (sb >> 2) + r);
#pragma unroll
    for (int t = 0; t < 4; t++)
#pragma unroll
      for (int r = 0; r < 4; r++) o[t][r] *= crr[r];

    s16x8 ap[2];
#pragma unroll
    for (int c = 0; c < 2; c++)
      ap[c] = load16B(&Ps[w][li * 72 + c * 32 + lg * 8]);

    // O += P @ V : B-frag from V^T rows (d = t*16+li)
    __builtin_amdgcn_s_setprio(1);
#pragma unroll
    for (int t = 0; t < 4; t++) {
#pragma unroll
      for (int c = 0; c < 2; c++) {
        int row = t * 16 + li;
        s16x8 bv = load16B((char*)Vts[cur] +
                           ((row * 128 + c * 64 + lg * 16) ^ ((row & 7) << 4)));
        o[t] = __builtin_amdgcn_mfma_f32_16x16x32_bf16(ap[c], bv, o[t], 0, 0, 0);
      }
    }
    __builtin_amdgcn_s_setprio(0);
    __syncthreads();
  }

  const int b = bh >> 4, h = bh & 15;
  const float inv = 1.0f / l_run;
  const int sb = (lane & 48);
  float invr[4];
#pragma unroll
  for (int r = 0; r < 4; r++) invr[r] = __shfl(inv, sb + (sb >> 2) + r);
#pragma unroll
  for (int r = 0; r < 4; r++)
#pragma unroll
    for (int t = 0; t < 4; t++) {
      size_t idx = (size_t)(b * SEQ + qrow + lg * 4 + r) * 1024 + h * 64 +
                   t * 16 + li;
      attn[idx] = __float2bfloat16(o[t][r] * invr[r]);
    }
}

extern "C" void kernel_launch(void* const* d_in, const int* in_sizes, int n_in,
                              void* d_out, int out_size, void* d_ws,
                              size_t ws_size, hipStream_t stream) {
  (void)in_sizes; (void)n_in; (void)out_size; (void)ws_size;
  const float* value = (const float*)d_in[0];
  const float* key   = (const float*)d_in[1];
  const float* query = (const float*)d_in[2];
  // d_in[3] = mask (int32 causal tril) — causality applied analytically
  const float* Wq_w = (const float*)d_in[4];
  const float* Wq_b = (const float*)d_in[5];
  const float* Wk_w = (const float*)d_in[6];
  const float* Wk_b = (const float*)d_in[7];
  const float* Wv_w = (const float*)d_in[8];
  const float* Wv_b = (const float*)d_in[9];
  // d_in[10..11] = Wr (computed-then-deleted in reference) — skipped
  const float* wo_w = (const float*)d_in[12];
  const float* wo_b = (const float*)d_in[13];

  bf16* ws = (bf16*)d_ws;
  const size_t MM = 1048576;
  bf16* WT   = ws;             // 4 transposed bf16 weights
  bf16* qbuf = ws + 4 * MM;    // [bh][l][64]
  bf16* kbuf = ws + 8 * MM;    // [bh][l][64]
  bf16* vtbf = ws + 12 * MM;   // [bh][64][l]
  bf16* abuf = ws + 16 * MM;   // [m][1024]  (total 40 MB)

  k_transpose<<<dim3(16, 16, 4), 256, 0, stream>>>(Wq_w, Wk_w, Wv_w, wo_w, WT);
  k_gemm_qkv<<<dim3(8, 32, 3), 256, 0, stream>>>(
      query, key, value, WT, Wq_b, Wk_b, Wv_b, qbuf, kbuf, vtbf);
  k_attn<<<dim3(32, 32), 256, 0, stream>>>(qbuf, kbuf, vtbf, abuf);
  k_gemm_out<<<dim3(8, 32), 256, 0, stream>>>(abuf, WT + 3 * MM, wo_b,
                                              (float*)d_out);
}

// Round 10
// 119.733 us; speedup vs baseline: 2.2185x; 1.1713x over previous
//
#include <hip/hip_runtime.h>
#include <hip/hip_bf16.h>
#include <type_traits>

typedef __hip_bfloat16 bf16;
typedef __attribute__((ext_vector_type(4))) float f32x4;
typedef __attribute__((ext_vector_type(8))) short s16x8;

#define DEVINL __device__ __forceinline__

DEVINL s16x8 load16B(const void* p) {
  s16x8 v;
  __builtin_memcpy(&v, __builtin_assume_aligned(p, 16), 16);
  return v;
}
DEVINL void store16B(void* p, s16x8 v) {
  __builtin_memcpy(__builtin_assume_aligned(p, 16), &v, 16);
}
// load 8 consecutive f32, downcast to 8 bf16 packed in s16x8
DEVINL s16x8 cvt8(const float* p) {
  f32x4 a, b;
  __builtin_memcpy(&a, __builtin_assume_aligned(p, 16), 16);
  __builtin_memcpy(&b, __builtin_assume_aligned(p + 4, 16), 16);
  union { s16x8 v; bf16 h[8]; } u;
#pragma unroll
  for (int i = 0; i < 4; i++) {
    u.h[i] = __float2bfloat16(a[i]);
    u.h[4 + i] = __float2bfloat16(b[i]);
  }
  return u.v;
}
// async global->LDS 16B (m97 pattern): LDS dest = wave-uniform base + lane*16
DEVINL void gload_lds16(const bf16* g, bf16* l) {
  __builtin_amdgcn_global_load_lds(
      (__attribute__((address_space(1))) void*)(void*)const_cast<bf16*>(g),
      (__attribute__((address_space(3))) void*)l, 16, 0, 0);
}

static constexpr int SEQ = 2048;   // L
// DX = 1024, H = 16, Dh = 64, B = 2 hard-coded below.

// ------ weight transpose + downcast: dst[n*1024+k] = bf16(src[k*1024+n]) ---
__global__ __launch_bounds__(256) void k_transpose(
    const float* __restrict__ Wq, const float* __restrict__ Wk,
    const float* __restrict__ Wv, const float* __restrict__ Wo,
    bf16* __restrict__ dst) {
  __shared__ float t[64][65];
  const float* src = blockIdx.z == 0 ? Wq : blockIdx.z == 1 ? Wk
                   : blockIdx.z == 2 ? Wv : Wo;
  bf16* out = dst + (size_t)blockIdx.z * 1024 * 1024;
  const int r0 = blockIdx.y * 64, c0 = blockIdx.x * 64;
#pragma unroll
  for (int i = 0; i < 16; i++) {
    int e = i * 256 + threadIdx.x;
    int r = e >> 6, c = e & 63;
    t[r][c] = src[(size_t)(r0 + r) * 1024 + c0 + c];
  }
  __syncthreads();
#pragma unroll
  for (int i = 0; i < 16; i++) {
    int e = i * 256 + threadIdx.x;
    int r = e >> 6, c = e & 63;
    out[(size_t)(c0 + r) * 1024 + r0 + c] = __float2bfloat16(t[c][r]);
  }
}

// -------- shared GEMM core: C = X[4096,1024] @ WT^T + bias ----------------
// WT bf16 [n][k] staged via global_load_lds; X either bf16 (gload_lds) or
// f32 (reg-stage + cvt + ds_write — fuses the downcast into the GEMM).
// mode 0: dst bf16 per-head token-major [bh][l][64], scaled (Q)  / K
// mode 1: dst bf16 per-head d-major     [bh][64][l]  (V^T)
// mode 2: dst f32 natural               [m][1024]    (final out)
template <typename XT>
DEVINL void gemm_core(const XT* __restrict__ X, const bf16* __restrict__ WT,
                      const float* __restrict__ bias, void* __restrict__ dstv,
                      const int mode, const float scale, const int m0,
                      const int n0) {
  __shared__ alignas(16) bf16 As[128 * 32];
  __shared__ alignas(16) bf16 Bs[128 * 32];
  const int tid = threadIdx.x;
  const int w = tid >> 6, lane = tid & 63, lg = lane >> 4, li = lane & 15;
  const int wm = w >> 1, wn = w & 1;

  f32x4 acc[4][4] = {};

  for (int kt = 0; kt < 32; ++kt) {
    const int k0 = kt * 32;
#pragma unroll
    for (int j = 0; j < 2; j++) {
      const int cb = (j * 4 + w) * 64;       // wave-uniform chunk base
      const int c = cb + lane;               // 16B chunk: row=c>>2, k=(c&3)*8
      const int r = c >> 2, kk = (c & 3) * 8;
      gload_lds16(WT + (size_t)(n0 + r) * 1024 + k0 + kk, Bs + cb * 8);
      if constexpr (std::is_same_v<XT, bf16>)
        gload_lds16(X + (size_t)(m0 + r) * 1024 + k0 + kk, As + cb * 8);
    }
    if constexpr (std::is_same_v<XT, float>) {  // fused cvt staging for A
#pragma unroll
      for (int j = 0; j < 2; j++) {
        const int c = j * 256 + tid;
        const int r = c >> 2, kk = (c & 3) * 8;
        s16x8 a = cvt8(X + (size_t)(m0 + r) * 1024 + k0 + kk);
        store16B((char*)As + c * 16, a);
      }
    }
    __syncthreads();   // drains vmcnt+lgkmcnt before s_barrier (m97)
    s16x8 af[4], bfv[4];
#pragma unroll
    for (int i = 0; i < 4; i++)
      af[i] = load16B((char*)As + (wm * 64 + i * 16 + li) * 64 + lg * 16);
#pragma unroll
    for (int j = 0; j < 4; j++)
      bfv[j] = load16B((char*)Bs + (wn * 64 + j * 16 + li) * 64 + lg * 16);
#pragma unroll
    for (int i = 0; i < 4; i++)
#pragma unroll
      for (int j = 0; j < 4; j++)
        acc[i][j] = __builtin_amdgcn_mfma_f32_16x16x32_bf16(af[i], bfv[j],
                                                            acc[i][j], 0, 0, 0);
    __syncthreads();   // all waves done reading before next overwrite
  }

  // C/D layout: lane reg r -> row (lane>>4)*4+r, col lane&15 (m89/m91)
#pragma unroll
  for (int j = 0; j < 4; j++) {
    const int n = n0 + wn * 64 + j * 16 + li;
    const float bv = bias[n];
#pragma unroll
    for (int i = 0; i < 4; i++) {
      const int mrow = m0 + wm * 64 + i * 16 + lg * 4;
      f32x4 a = acc[i][j];
      if (mode == 2) {
        float* dst = (float*)dstv;
#pragma unroll
        for (int r = 0; r < 4; r++)
          dst[(size_t)(mrow + r) * 1024 + n] = a[r] + bv;
      } else if (mode == 0) {
        bf16* dst = (bf16*)dstv;
#pragma unroll
        for (int r = 0; r < 4; r++) {
          int m = mrow + r;   // b=m>>11, l=m&2047, h=n>>6, d=n&63
          size_t idx =
              ((size_t)((m >> 11) * 16 + (n >> 6)) * SEQ + (m & 2047)) * 64 +
              (n & 63);
          dst[idx] = __float2bfloat16((a[r] + bv) * scale);
        }
      } else {  // mode 1: V^T, 4 consecutive tokens same d -> one 8B store
        bf16* dst = (bf16*)dstv;
        size_t base =
            ((size_t)((mrow >> 11) * 16 + (n >> 6)) * 64 + (n & 63)) * SEQ +
            (mrow & 2047);
        bf16 tmp[4];
#pragma unroll
        for (int r = 0; r < 4; r++) tmp[r] = __float2bfloat16(a[r] + bv);
        __builtin_memcpy(__builtin_assume_aligned(dst + base, 8), tmp, 8);
      }
    }
  }
}

// fused Q/K/V projections from f32 inputs (cvt fused into staging)
// grid (x = m-block 32, y = n-block 8, z = 3): id%8 = mx%8 -> the 8 n-blocks
// sharing one A-panel are co-XCD; per-XCD/z working set = 2MB A + 2MB B = L2.
__global__ __launch_bounds__(256) void k_gemm_qkv(
    const float* __restrict__ qx, const float* __restrict__ kx,
    const float* __restrict__ vx, const bf16* __restrict__ WTbase,
    const float* __restrict__ qb, const float* __restrict__ kb,
    const float* __restrict__ vb, bf16* __restrict__ qo,
    bf16* __restrict__ ko, bf16* __restrict__ vto) {
  const int z = blockIdx.z;
  const float* X = z == 0 ? qx : z == 1 ? kx : vx;
  const bf16* WT = WTbase + (size_t)z * 1048576;
  const float* bias = z == 0 ? qb : z == 1 ? kb : vb;
  void* dst = z == 0 ? (void*)qo : z == 1 ? (void*)ko : (void*)vto;
  gemm_core<float>(X, WT, bias, dst, z == 2 ? 1 : 0, z == 0 ? 0.03125f : 1.0f,
                   blockIdx.x * 128, blockIdx.y * 128);
}

__global__ __launch_bounds__(256) void k_gemm_out(
    const bf16* __restrict__ X, const bf16* __restrict__ WT,
    const float* __restrict__ bias, float* __restrict__ out) {
  gemm_core<bf16>(X, WT, bias, out, 2, 1.0f, blockIdx.x * 128,
                  blockIdx.y * 128);
}

// ------------------------- causal flash attention --------------------------
// grid (x=bh 32, y=qy 32), qblk = 31-qy. bh in x => per-CU qblk mix
// {31-q0,23-q0,15-q0,7-q0} (balanced, heaviest dispatched first) and all
// blocks of one bh share an XCD (id%8 = bh%8) for K/V L2 locality.
// SWAPPED QK^T: S^T = mfma(K,Q) -> lane (lg,li) holds 16 scores of q-row li.
// Double-buffered K/V LDS, 1 barrier/iter. Q pre-scaled by 1/32.
__global__ __launch_bounds__(256) void k_attn(
    const bf16* __restrict__ qb, const bf16* __restrict__ kb,
    const bf16* __restrict__ vtb, bf16* __restrict__ attn) {
  __shared__ alignas(16) bf16 Ks[2][64 * 64];   // [buf][k][d], XOR-swizzled
  __shared__ alignas(16) bf16 Vts[2][64 * 64];  // [buf][d][k], XOR-swizzled
  __shared__ alignas(16) bf16 Ps[4][16 * 72];   // per-wave P [q=li][k], +8 pad
  const int tid = threadIdx.x;
  const int w = tid >> 6, lane = tid & 63, lg = lane >> 4, li = lane & 15;
  const int bh = blockIdx.x;
  const int qblk = 31 - blockIdx.y;             // heaviest first
  const int qrow = qblk * 64 + w * 16;
  const bf16* qh = qb + (size_t)bh * SEQ * 64;
  const bf16* kh = kb + (size_t)bh * SEQ * 64;
  const bf16* vth = vtb + (size_t)bh * 64 * SEQ;

  s16x8 aq[2];  // Q fragments (B-operand now) held in registers all kernel
#pragma unroll
  for (int c = 0; c < 2; c++)
    aq[c] = load16B(qh + (size_t)(qrow + li) * 64 + c * 32 + lg * 8);

  f32x4 o[4] = {};
  float m_run = -1e38f;   // per-lane: stats of q-row (qrow + li)
  float l_run = 0.f;

  // staging helpers (register prefetch -> swizzled LDS write)
  const int c0s = tid, c1s = 256 + tid;
  const int by0 = (c0s * 16) ^ (((c0s >> 3) & 7) << 4);
  const int by1 = (c1s * 16) ^ (((c1s >> 3) & 7) << 4);
  const int d0 = c0s >> 3, kk0 = (c0s & 7) * 8;
  const int d1 = c1s >> 3, kk1 = (c1s & 7) * 8;

  s16x8 rk[2], rv[2];
  // prologue: tile 0 -> regs -> buf0; prefetch tile 1 -> regs
  rk[0] = load16B(kh + (size_t)c0s * 8);
  rk[1] = load16B(kh + (size_t)c1s * 8);
  rv[0] = load16B(vth + (size_t)d0 * SEQ + kk0);
  rv[1] = load16B(vth + (size_t)d1 * SEQ + kk1);
  store16B((char*)Ks[0] + by0, rk[0]);
  store16B((char*)Ks[0] + by1, rk[1]);
  store16B((char*)Vts[0] + by0, rv[0]);
  store16B((char*)Vts[0] + by1, rv[1]);
  if (qblk >= 1) {
    rk[0] = load16B(kh + (size_t)64 * 64 + c0s * 8);
    rk[1] = load16B(kh + (size_t)64 * 64 + c1s * 8);
    rv[0] = load16B(vth + (size_t)d0 * SEQ + 64 + kk0);
    rv[1] = load16B(vth + (size_t)d1 * SEQ + 64 + kk1);
  }
  __syncthreads();

  for (int kbk = 0; kbk <= qblk; ++kbk) {
    const int cur = kbk & 1;
    if (kbk < qblk) {                 // write tile kbk+1 to alt buffer
      store16B((char*)Ks[cur ^ 1] + by0, rk[0]);
      store16B((char*)Ks[cur ^ 1] + by1, rk[1]);
      store16B((char*)Vts[cur ^ 1] + by0, rv[0]);
      store16B((char*)Vts[cur ^ 1] + by1, rv[1]);
      if (kbk + 2 <= qblk) {          // issue loads for tile kbk+2
        const int kn = (kbk + 2) * 64;
        rk[0] = load16B(kh + (size_t)kn * 64 + c0s * 8);
        rk[1] = load16B(kh + (size_t)kn * 64 + c1s * 8);
        rv[0] = load16B(vth + (size_t)d0 * SEQ + kn + kk0);
        rv[1] = load16B(vth + (size_t)d1 * SEQ + kn + kk1);
      }
    }

    // S^T = K Q^T : A-frag = K rows, B-frag = Q rows
    // s[t][r] = S[q = qrow+li][k = kbk*64 + t*16 + lg*4 + r]
    f32x4 s[4];
    __builtin_amdgcn_s_setprio(1);
#pragma unroll
    for (int t = 0; t < 4; t++) {
      f32x4 z = {};
#pragma unroll
      for (int c = 0; c < 2; c++) {
        int row = t * 16 + li;
        s16x8 ak = load16B((char*)Ks[cur] +
                           ((row * 128 + c * 64 + lg * 16) ^ ((row & 7) << 4)));
        z = __builtin_amdgcn_mfma_f32_16x16x32_bf16(ak, aq[c], z, 0, 0, 0);
      }
      s[t] = z;
    }
    __builtin_amdgcn_s_setprio(0);

    if (kbk == qblk) {  // diagonal block: per-element causal mask
      const int kb0 = kbk * 64 + lg * 4;
      const int qg = qrow + li;
#pragma unroll
      for (int t = 0; t < 4; t++)
#pragma unroll
        for (int r = 0; r < 4; r++)
          if (kb0 + t * 16 + r > qg) s[t][r] = -1e30f;
    }

    // softmax for all 16 q-rows at once: in-lane tree + xor16/xor32
    f32x4 mm = s[0];
#pragma unroll
    for (int t = 1; t < 4; t++)
#pragma unroll
      for (int r = 0; r < 4; r++) mm[r] = fmaxf(mm[r], s[t][r]);
    float mr = fmaxf(fmaxf(mm[0], mm[1]), fmaxf(mm[2], mm[3]));
    mr = fmaxf(mr, __shfl_xor(mr, 16));
    mr = fmaxf(mr, __shfl_xor(mr, 32));
    const float mn = fmaxf(m_run, mr);

    float p[4][4];
    float sum = 0.f;
#pragma unroll
    for (int t = 0; t < 4; t++)
#pragma unroll
      for (int r = 0; r < 4; r++) {
        float pv = __expf(s[t][r] - mn);
        p[t][r] = pv;
        sum += pv;
      }
    sum += __shfl_xor(sum, 16);
    sum += __shfl_xor(sum, 32);
    const float cr = __expf(m_run - mn);
    l_run = l_run * cr + sum;
    m_run = mn;

    // P -> per-wave LDS in [q=li][k] layout (8B packed stores)
#pragma unroll
    for (int t = 0; t < 4; t++) {
      bf16 tmp[4];
#pragma unroll
      for (int r = 0; r < 4; r++) tmp[r] = __float2bfloat16(p[t][r]);
      __builtin_memcpy(
          __builtin_assume_aligned(&Ps[w][li * 72 + t * 16 + lg * 4], 8), tmp,
          8);
    }

    // rescale O: row (qrow + lg*4 + r) stats live at lane li = lg*4+r
    const int sb = (lane & 48);
    float crr[4];
#pragma unroll
    for (int r = 0; r < 4; r++) crr[r] = __shfl(cr, sb + (sb >> 2) + r);
#pragma unroll
    for (int t = 0; t < 4; t++)
#pragma unroll
      for (int r = 0; r < 4; r++) o[t][r] *= crr[r];

    s16x8 ap[2];
#pragma unroll
    for (int c = 0; c < 2; c++)
      ap[c] = load16B(&Ps[w][li * 72 + c * 32 + lg * 8]);

    // O += P @ V : B-frag from V^T rows (d = t*16+li)
    __builtin_amdgcn_s_setprio(1);
#pragma unroll
    for (int t = 0; t < 4; t++) {
#pragma unroll
      for (int c = 0; c < 2; c++) {
        int row = t * 16 + li;
        s16x8 bv = load16B((char*)Vts[cur] +
                           ((row * 128 + c * 64 + lg * 16) ^ ((row & 7) << 4)));
        o[t] = __builtin_amdgcn_mfma_f32_16x16x32_bf16(ap[c], bv, o[t], 0, 0, 0);
      }
    }
    __builtin_amdgcn_s_setprio(0);
    __syncthreads();
  }

  const int b = bh >> 4, h = bh & 15;
  const float inv = 1.0f / l_run;
  const int sb = (lane & 48);
  float invr[4];
#pragma unroll
  for (int r = 0; r < 4; r++) invr[r] = __shfl(inv, sb + (sb >> 2) + r);
#pragma unroll
  for (int r = 0; r < 4; r++)
#pragma unroll
    for (int t = 0; t < 4; t++) {
      size_t idx = (size_t)(b * SEQ + qrow + lg * 4 + r) * 1024 + h * 64 +
                   t * 16 + li;
      attn[idx] = __float2bfloat16(o[t][r] * invr[r]);
    }
}

extern "C" void kernel_launch(void* const* d_in, const int* in_sizes, int n_in,
                              void* d_out, int out_size, void* d_ws,
                              size_t ws_size, hipStream_t stream) {
  (void)in_sizes; (void)n_in; (void)out_size; (void)ws_size;
  const float* value = (const float*)d_in[0];
  const float* key   = (const float*)d_in[1];
  const float* query = (const float*)d_in[2];
  // d_in[3] = mask (int32 causal tril) — causality applied analytically
  const float* Wq_w = (const float*)d_in[4];
  const float* Wq_b = (const float*)d_in[5];
  const float* Wk_w = (const float*)d_in[6];
  const float* Wk_b = (const float*)d_in[7];
  const float* Wv_w = (const float*)d_in[8];
  const float* Wv_b = (const float*)d_in[9];
  // d_in[10..11] = Wr (computed-then-deleted in reference) — skipped
  const float* wo_w = (const float*)d_in[12];
  const float* wo_b = (const float*)d_in[13];

  bf16* ws = (bf16*)d_ws;
  const size_t MM = 1048576;
  bf16* WT   = ws;             // 4 transposed bf16 weights
  bf16* qbuf = ws + 4 * MM;    // [bh][l][64]
  bf16* kbuf = ws + 8 * MM;    // [bh][l][64]
  bf16* vtbf = ws + 12 * MM;   // [bh][64][l]
  bf16* abuf = ws + 16 * MM;   // [m][1024]  (total 40 MB)

  k_transpose<<<dim3(16, 16, 4), 256, 0, stream>>>(Wq_w, Wk_w, Wv_w, wo_w, WT);
  k_gemm_qkv<<<dim3(32, 8, 3), 256, 0, stream>>>(
      query, key, value, WT, Wq_b, Wk_b, Wv_b, qbuf, kbuf, vtbf);
  k_attn<<<dim3(32, 32), 256, 0, stream>>>(qbuf, kbuf, vtbf, abuf);
  k_gemm_out<<<dim3(32, 8), 256, 0, stream>>>(abuf, WT + 3 * MM, wo_b,
                                              (float*)d_out);
}